// Round 10
// baseline (150.251 us; speedup 1.0000x reference)
//
#include <hip/hip_runtime.h>
#include <hip/hip_fp16.h>
#include <stdint.h>

// deform_conv2d: N=8, C=256, H=W=64, OC=256, 3x3, stride=1, pad=1 -> OH=OW=64
// im2col-fused MFMA GEMM. M=32768 (n,oh,ow), N=256 oc, K=2304 (kd = k*256+c).
// R16: LDS-traffic cut via fat wave tiles. R13(8 waves/CU) == R15(16 waves/CU)
//   == 63us proves TLP is not binding; corrected LDS audit shows the LDS data
//   pipe at ~71% busy (192 frag wave-reads + DMA/stage writes ~3.0K cyc of a
//   4.2K cyc wall) -- the queue is the soft wall. Fragment reads scale as
//   (1/m_w + 1/n_w): switch 8x(32x64) waves -> 4x(64x64) waves (acc[4][4]):
//   16 reads / 32 MFMA vs 12/16 => -33% LDS read traffic, same block tile
//   (64 rows x 256 oc), same 80KB LDS / 2 blocks/CU, same counted schedule.
//   Each thread stages 2 units sharing ONE coords entry (groups sg, sg+4 of
//   the same row): coords loads halve, weights shared, 2nd gather addr =
//   1st + 64B. Waits: AMATH vmcnt(8) (retire 8 gathers, keep 8 DMA; 9 on
//   coords iters), EBAR vmcnt(0) retires chunk-aged DMA only.

typedef _Float16 half8 __attribute__((ext_vector_type(8)));
typedef float f32x4 __attribute__((ext_vector_type(4)));

__device__ __forceinline__ __half2 h2(uint32_t u) {
  return __builtin_bit_cast(__half2, u);
}
__device__ __forceinline__ uint32_t packh2f(float a, float b) {
  return __builtin_bit_cast(uint32_t, __floats2half2_rn(a, b));
}
__device__ __forceinline__ __half2 duplo(uint32_t u) {
  return __half2half2(__builtin_bit_cast(__half, (unsigned short)(u & 0xffffu)));
}
__device__ __forceinline__ __half2 duphi(uint32_t u) {
  return __half2half2(__builtin_bit_cast(__half, (unsigned short)(u >> 16)));
}

// ---- merged prep: [0,2048) x NCHW fp32 -> NHWC f16
//                   [2048,4352) weights -> wave-contiguous f16 panels
//                   [4352,5504) offsets -> packed coords {4 x f16 w, 4 x u16 pix}
__global__ __launch_bounds__(256) void prep_all_kernel(
    const float* __restrict__ x, const float* __restrict__ w,
    const float* __restrict__ offset,
    unsigned short* __restrict__ xb, unsigned short* __restrict__ w3s,
    unsigned short* __restrict__ coords) {
  __shared__ float tile[64][65];
  int tid = threadIdx.x;
  if (blockIdx.x < 2048) {
    int bn   = blockIdx.x >> 8;
    int rem  = blockIdx.x & 255;
    int y    = rem >> 2;
    int cblk = rem & 3;
    const float* src = x + ((size_t)(bn * 256 + cblk * 64)) * 4096 + y * 64;
#pragma unroll
    for (int i = 0; i < 4; ++i) {
      int u  = i * 256 + tid;
      int cl = u >> 4;
      int xs = (u & 15) * 4;
      float4 v = *(const float4*)(src + cl * 4096 + xs);
      tile[cl][xs] = v.x; tile[cl][xs + 1] = v.y;
      tile[cl][xs + 2] = v.z; tile[cl][xs + 3] = v.w;
    }
    __syncthreads();
    unsigned short* dst = xb + ((size_t)(bn * 64 + y) * 64) * 256 + cblk * 64;
#pragma unroll
    for (int i = 0; i < 8; ++i) {
      int v2  = i * 256 + tid;
      int xc  = v2 >> 5;
      int cl2 = (v2 & 31) * 2;
      *(uint32_t*)(dst + xc * 256 + cl2) = packh2f(tile[cl2][xc], tile[cl2 + 1][xc]);
    }
  } else if (blockIdx.x < 4352) {
    // w3s layout: chunk t (16384 shorts) = [wcol(4)][nn(4)][ks(2)][lane(64)][e(8)]
    int idx = (blockIdx.x - 2048) * 256 + tid;   // < 589824
    int t    = idx >> 14;
    int r2   = idx & 16383;
    int e    = r2 & 7;
    int lane = (r2 >> 3) & 63;
    int ks   = (r2 >> 9) & 1;
    int nn   = (r2 >> 10) & 3;
    int wcol = (r2 >> 12) & 3;
    int oc = wcol * 64 + nn * 16 + (lane & 15);
    int kk = (ks * 4 + (lane >> 4)) * 8 + e;
    int c  = (t & 3) * 64 + kk;
    int k  = t >> 2;
    w3s[idx] = __builtin_bit_cast(unsigned short, __float2half(w[(oc * 256 + c) * 9 + k]));
  } else {
    int idx = (blockIdx.x - 4352) * 256 + tid;   // < 294912
    int ow  = idx & 63;
    int oh  = (idx >> 6) & 63;
    int r   = idx >> 12;          // bn*9 + k
    int k   = r % 9;
    int bn  = r / 9;
    int ky = k / 3 - 1;
    int kx = k % 3 - 1;
    float offy = offset[((bn * 18 + 2 * k    ) * 64 + oh) * 64 + ow];
    float offx = offset[((bn * 18 + 2 * k + 1) * 64 + oh) * 64 + ow];
    float y = (float)(oh + ky) + offy;
    float x2 = (float)(ow + kx) + offx;
    float y0f = floorf(y), x0f = floorf(x2);
    float fy = y - y0f, fx = x2 - x0f;
    int y0 = (int)y0f, x0 = (int)x0f;
    int y1 = y0 + 1, x1 = x0 + 1;
    float vy0 = (y0 >= 0 && y0 <= 63) ? 1.0f : 0.0f;
    float vy1 = (y1 >= 0 && y1 <= 63) ? 1.0f : 0.0f;
    float vx0 = (x0 >= 0 && x0 <= 63) ? 1.0f : 0.0f;
    float vx1 = (x1 >= 0 && x1 <= 63) ? 1.0f : 0.0f;
    float wy0 = (1.0f - fy) * vy0, wy1 = fy * vy1;
    float wx0 = (1.0f - fx) * vx0, wx1 = fx * vx1;
    int y0c = min(max(y0, 0), 63), y1c = min(max(y1, 0), 63);
    int x0c = min(max(x0, 0), 63), x1c = min(max(x1, 0), 63);
    unsigned short ent[8];
    ent[0] = __builtin_bit_cast(unsigned short, __float2half(wy0 * wx0));
    ent[1] = __builtin_bit_cast(unsigned short, __float2half(wy0 * wx1));
    ent[2] = __builtin_bit_cast(unsigned short, __float2half(wy1 * wx0));
    ent[3] = __builtin_bit_cast(unsigned short, __float2half(wy1 * wx1));
    ent[4] = (unsigned short)(y0c * 64 + x0c);
    ent[5] = (unsigned short)(y0c * 64 + x1c);
    ent[6] = (unsigned short)(y1c * 64 + x0c);
    ent[7] = (unsigned short)(y1c * 64 + x1c);
    *(uint4*)(coords + (size_t)idx * 8) = *(const uint4*)ent;
  }
}

// ---- main: 512 blocks x 256 threads; tile 64 rows x 256 oc; wave 64x64 ----
__global__ __launch_bounds__(256, 2) void deform_mfma_kernel(
    const unsigned short* __restrict__ xb,      // NHWC f16
    const unsigned short* __restrict__ coords,  // packed coord entries
    const unsigned short* __restrict__ w3s,     // wave-contiguous panels f16
    float* __restrict__ out) {                  // (8, 256, 64, 64) fp32
  // At 2x8KB (XOR group swizzle) + Bt 2x32KB (linear DMA image) = 80KB exactly
  // -> 2 blocks/CU (8 waves/CU; R13 proved 8 waves suffice).
  __shared__ __align__(16) unsigned short At[2][64 * 64];
  __shared__ __align__(16) unsigned short Bt[2][16384];

  int bn  = blockIdx.x & 7;      // XCD swizzle
  int oh  = blockIdx.x >> 3;     // 0..63
  int tid = threadIdx.x;

  int w    = tid >> 6;            // wave 0..3 -> 64-oc band
  int lane = tid & 63;
  int mrow = lane & 15;
  int quad = lane >> 4;

  // staging identity: one thread = rows' (srow) groups {sgl, sgl+4}
  int srow = tid >> 2;             // 0..63
  int sgl  = tid & 3;

  const char* xbc = (const char*)(xb + (size_t)bn * (64 * 64 * 256));
  const unsigned short* cb = coords + ((size_t)((bn * 9) * 64 + oh) * 64 + srow) * 8;

  int aw0  = srow * 64 + ((sgl ^ (srow & 7)) * 8);        // unit A slot (shorts)
  int aw1  = srow * 64 + (((sgl + 4) ^ (srow & 7)) * 8);  // unit B slot
  int grp0 = quad ^ (mrow & 7);                           // ks=0 A frag group
  int grp1 = (4 + quad) ^ (mrow & 7);                     // ks=1 A frag group
  int a_row = mrow * 64;                                  // + m*1024 (shorts)
  int b_off = w * 4096 + lane * 8;                        // shorts; + (nn*2+ks)*512

  f32x4 acc[4][4] = {};

  __half2 w00, w01, w02, w03;
  uint32_t o00, o01, o02, o03;            // unit A offsets; unit B = +64 bytes
  uint4 cn;
  uint4 ga0, ga1, ga2, ga3;               // unit A corner gathers
  uint4 gb0, gb1, gb2, gb3;               // unit B corner gathers

  // ENTRY barrier: retire chunk-aged DMA + all-wave Bt visibility.
#define EBAR()                                                                  \
  {                                                                             \
    asm volatile("s_waitcnt vmcnt(0) lgkmcnt(0)" ::: "memory");                 \
    __builtin_amdgcn_sched_barrier(0);                                          \
    __builtin_amdgcn_s_barrier();                                               \
    asm volatile("" ::: "memory");                                              \
  }
  // EXIT barrier: LDS-order only; fresh DMA crosses in flight (T4).
#define CBAR()                                                                  \
  {                                                                             \
    asm volatile("s_waitcnt lgkmcnt(0)" ::: "memory");                          \
    __builtin_amdgcn_s_barrier();                                               \
    asm volatile("" ::: "memory");                                              \
  }
#define VMW(N)                                                                  \
  {                                                                             \
    asm volatile("s_waitcnt vmcnt(" #N ")" ::: "memory");                       \
    __builtin_amdgcn_sched_barrier(0);                                          \
  }

  // B chunk -> LDS via DMA: 8 x 1KB per wave (wave w owns its 8KB oc-band)
#define BDMA(TT, BB)                                                            \
  {                                                                             \
    const unsigned short* src = w3s + (size_t)(TT) * 16384 + b_off;             \
    unsigned short* dst = &Bt[BB][0] + b_off;                                   \
    _Pragma("unroll")                                                           \
    for (int j = 0; j < 8; ++j) {                                               \
      __builtin_amdgcn_global_load_lds(                                         \
          (const __attribute__((address_space(1))) void*)(src + j * 512),       \
          (__attribute__((address_space(3))) void*)(dst + j * 512),             \
          16, 0, 0);                                                            \
    }                                                                           \
  }

#define TAPSETUP_R(CE)                                                          \
  {                                                                             \
    w00 = duplo((CE).x); w01 = duphi((CE).x);                                   \
    w02 = duplo((CE).y); w03 = duphi((CE).y);                                   \
    o00 = (((CE).z & 0xffffu) << 9) + sgl * 16;                                 \
    o01 = (((CE).z >> 16) << 9) + sgl * 16;                                     \
    o02 = (((CE).w & 0xffffu) << 9) + sgl * 16;                                 \
    o03 = (((CE).w >> 16) << 9) + sgl * 16;                                     \
  }

  // 8 corner gathers: unit A (group sgl) + unit B (group sgl+4, +64 B)
#define AGATHER(TT)                                                             \
  {                                                                             \
    ga0 = *(const uint4*)(xbc + o00 + ((TT) & 3) * 128);                        \
    ga1 = *(const uint4*)(xbc + o01 + ((TT) & 3) * 128);                        \
    ga2 = *(const uint4*)(xbc + o02 + ((TT) & 3) * 128);                        \
    ga3 = *(const uint4*)(xbc + o03 + ((TT) & 3) * 128);                        \
    gb0 = *(const uint4*)(xbc + o00 + ((TT) & 3) * 128 + 64);                   \
    gb1 = *(const uint4*)(xbc + o01 + ((TT) & 3) * 128 + 64);                   \
    gb2 = *(const uint4*)(xbc + o02 + ((TT) & 3) * 128 + 64);                   \
    gb3 = *(const uint4*)(xbc + o03 + ((TT) & 3) * 128 + 64);                   \
  }

  // both units' bilinear combine + 2 LDS writes; VM retires gathers, keeps DMA
#define AMATH(ATP, VM)                                                          \
  {                                                                             \
    VMW(VM)                                                                     \
    __half2 r0 = __hmul2(h2(ga0.x), w00);                                       \
    r0 = __hfma2(h2(ga1.x), w01, r0); r0 = __hfma2(h2(ga2.x), w02, r0);         \
    r0 = __hfma2(h2(ga3.x), w03, r0);                                           \
    __half2 r1 = __hmul2(h2(ga0.y), w00);                                       \
    r1 = __hfma2(h2(ga1.y), w01, r1); r1 = __hfma2(h2(ga2.y), w02, r1);         \
    r1 = __hfma2(h2(ga3.y), w03, r1);                                           \
    __half2 r2 = __hmul2(h2(ga0.z), w00);                                       \
    r2 = __hfma2(h2(ga1.z), w01, r2); r2 = __hfma2(h2(ga2.z), w02, r2);         \
    r2 = __hfma2(h2(ga3.z), w03, r2);                                           \
    __half2 r3 = __hmul2(h2(ga0.w), w00);                                       \
    r3 = __hfma2(h2(ga1.w), w01, r3); r3 = __hfma2(h2(ga2.w), w02, r3);         \
    r3 = __hfma2(h2(ga3.w), w03, r3);                                           \
    uint4 pk;                                                                   \
    pk.x = __builtin_bit_cast(uint32_t, r0);                                    \
    pk.y = __builtin_bit_cast(uint32_t, r1);                                    \
    pk.z = __builtin_bit_cast(uint32_t, r2);                                    \
    pk.w = __builtin_bit_cast(uint32_t, r3);                                    \
    *(uint4*)((ATP) + aw0) = pk;                                                \
    __half2 s0 = __hmul2(h2(gb0.x), w00);                                       \
    s0 = __hfma2(h2(gb1.x), w01, s0); s0 = __hfma2(h2(gb2.x), w02, s0);         \
    s0 = __hfma2(h2(gb3.x), w03, s0);                                           \
    __half2 s1 = __hmul2(h2(gb0.y), w00);                                       \
    s1 = __hfma2(h2(gb1.y), w01, s1); s1 = __hfma2(h2(gb2.y), w02, s1);         \
    s1 = __hfma2(h2(gb3.y), w03, s1);                                           \
    __half2 s2 = __hmul2(h2(gb0.z), w00);                                       \
    s2 = __hfma2(h2(gb1.z), w01, s2); s2 = __hfma2(h2(gb2.z), w02, s2);         \
    s2 = __hfma2(h2(gb3.z), w03, s2);                                           \
    __half2 s3 = __hmul2(h2(gb0.w), w00);                                       \
    s3 = __hfma2(h2(gb1.w), w01, s3); s3 = __hfma2(h2(gb2.w), w02, s3);         \
    s3 = __hfma2(h2(gb3.w), w03, s3);                                           \
    uint4 qk;                                                                   \
    qk.x = __builtin_bit_cast(uint32_t, s0);                                    \
    qk.y = __builtin_bit_cast(uint32_t, s1);                                    \
    qk.z = __builtin_bit_cast(uint32_t, s2);                                    \
    qk.w = __builtin_bit_cast(uint32_t, s3);                                    \
    *(uint4*)((ATP) + aw1) = qk;                                                \
  }

  // 8 af + 8 bfr ds_reads, 32 MFMA; no vmem wait (EBAR/CBAR guarantee data)
#define COMPUTE(ATP, BTP)                                                       \
  {                                                                             \
    half8 bfr[2][4];                                                            \
    _Pragma("unroll")                                                           \
    for (int nn = 0; nn < 4; ++nn) {                                            \
      bfr[0][nn] = *(const half8*)((BTP) + b_off + (nn * 2 + 0) * 512);         \
      bfr[1][nn] = *(const half8*)((BTP) + b_off + (nn * 2 + 1) * 512);         \
    }                                                                           \
    __builtin_amdgcn_s_setprio(1);                                              \
    _Pragma("unroll")                                                           \
    for (int m = 0; m < 4; ++m) {                                               \
      half8 af0 = *(const half8*)((ATP) + m * 1024 + a_row + grp0 * 8);         \
      half8 af1 = *(const half8*)((ATP) + m * 1024 + a_row + grp1 * 8);         \
      _Pragma("unroll")                                                         \
      for (int nn = 0; nn < 4; ++nn) {                                          \
        acc[m][nn] = __builtin_amdgcn_mfma_f32_16x16x32_f16(af0, bfr[0][nn], acc[m][nn], 0, 0, 0); \
        acc[m][nn] = __builtin_amdgcn_mfma_f32_16x16x32_f16(af1, bfr[1][nn], acc[m][nn], 0, 0, 0); \
      }                                                                         \
    }                                                                           \
    __builtin_amdgcn_s_setprio(0);                                              \
  }

  // ---- prologue: coords, gathers(0), DMA(0)->Bt[0], stage A(0) ----
  {
    uint4 ce0 = *(const uint4*)cb;
    TAPSETUP_R(ce0)
  }
  AGATHER(0)
  BDMA(0, 0)
  AMATH(&At[0][0], 8)                // retire 8 gathers, keep 8 DMA in flight
  CBAR()

  for (int tap = 0; tap < 9; ++tap) {
#pragma unroll
    for (int cc = 0; cc < 4; ++cc) {
      const int t = tap * 4 + cc;
      // ---- ENTRY: retire DMA(t) (chunk-aged), all-wave Bt visibility ----
      EBAR()
      // ---- issue t+1 vmem: gathers (oldest), coords, DMA (newest) ----
      if (t < 35) {
        if (cc == 3) TAPSETUP_R(cn)       // VALU-only; cn retired by EBAR
        AGATHER(t + 1)
        if (cc == 2 && tap < 8) cn = *(const uint4*)(cb + (tap + 1) * 32768);
        if (cc & 1) { BDMA(t + 1, 0) } else { BDMA(t + 1, 1) }
      }
      // ---- compute chunk t (no vmem wait) ----
      if (cc & 1) { COMPUTE(&At[1][0], &Bt[1][0]) } else { COMPUTE(&At[0][0], &Bt[0][0]) }
      // ---- finish A(t+1): retire gathers (+cn on coords iters), keep DMA ----
      if (t < 35) {
        if (cc & 1) {
          AMATH(&At[0][0], 8)
        } else if (cc == 2 && tap < 8) {
          AMATH(&At[1][0], 9)
        } else {
          AMATH(&At[1][0], 8)
        }
      }
      // ---- EXIT: LDS order only; DMA(t+1) crosses in flight ----
      CBAR()
    }
  }

  // ---- epilogue: C/D layout col=lane&15(oc), row=quad*4+reg(ow) ----
  float* outp = out + (size_t)bn * 256 * 4096 + (size_t)oh * 64;
#pragma unroll
  for (int m = 0; m < 4; ++m) {
    int ow0 = m * 16 + quad * 4;
#pragma unroll
    for (int nn = 0; nn < 4; ++nn) {
      int oc = w * 64 + nn * 16 + mrow;
      *(f32x4*)(outp + (size_t)oc * 4096 + ow0) = acc[m][nn];
    }
  }
#undef EBAR
#undef CBAR
#undef VMW
#undef BDMA
#undef TAPSETUP_R
#undef AGATHER
#undef AMATH
#undef COMPUTE
}

extern "C" void kernel_launch(void* const* d_in, const int* in_sizes, int n_in,
                              void* d_out, int out_size, void* d_ws, size_t ws_size,
                              hipStream_t stream) {
  (void)in_sizes; (void)n_in; (void)out_size; (void)ws_size;
  const float* x      = (const float*)d_in[0];
  const float* offset = (const float*)d_in[1];
  const float* weight = (const float*)d_in[2];
  float* out = (float*)d_out;

  unsigned short* xb     = (unsigned short*)d_ws;                        // 16.78 MB
  unsigned short* w3s    = xb + (size_t)8 * 64 * 64 * 256;               // +1.18 MB
  unsigned short* coords = w3s + (size_t)36 * 16384;                     // +4.72 MB

  prep_all_kernel<<<5504, 256, 0, stream>>>(x, weight, offset, xb, w3s, coords);
  deform_mfma_kernel<<<512, 256, 0, stream>>>(xb, coords, w3s, out);
}

// Round 11
// 148.196 us; speedup vs baseline: 1.0139x; 1.0139x over previous
//
#include <hip/hip_runtime.h>
#include <hip/hip_fp16.h>
#include <stdint.h>

// deform_conv2d: N=8, C=256, H=W=64, OC=256, 3x3, stride=1, pad=1 -> OH=OW=64
// im2col-fused MFMA GEMM. M=32768 (n,oh,ow), N=256 oc, K=2304 (kd = k*256+c).
// R17: prep rewrite; main kernel = R15 verbatim (best: 62.8us, 0 conflicts).
//   Total-vs-main accounting: main 63us, total 140.7us -- a ~78us residual
//   constant across 11 rounds. Prep BW floor is ~12us (x=33.5MB fp32 ->
//   xb=16.8MB f16) but the round-0 x-prep (LDS transpose, 128B-segment
//   writes, syncthreads) was never touched. New x-prep: pure REGISTER
//   transpose -- thread owns 8ch x 4x: 8x float4 reads (neighbor threads
//   consume the other quarters of each 64B line), cvt+pack in regs, 4x16B
//   stores with 32 lanes contiguous (512B runs, fully coalesced, no LDS,
//   no barrier). 1024 blocks. Weights/coords prep unchanged (ranges shift).

typedef _Float16 half8 __attribute__((ext_vector_type(8)));
typedef float f32x4 __attribute__((ext_vector_type(4)));

__device__ __forceinline__ __half2 h2(uint32_t u) {
  return __builtin_bit_cast(__half2, u);
}
__device__ __forceinline__ uint32_t packh2f(float a, float b) {
  return __builtin_bit_cast(uint32_t, __floats2half2_rn(a, b));
}
__device__ __forceinline__ __half2 duplo(uint32_t u) {
  return __half2half2(__builtin_bit_cast(__half, (unsigned short)(u & 0xffffu)));
}
__device__ __forceinline__ __half2 duphi(uint32_t u) {
  return __half2half2(__builtin_bit_cast(__half, (unsigned short)(u >> 16)));
}

// ---- merged prep: [0,1024)     x NCHW fp32 -> NHWC f16 (register transpose)
//                   [1024,3328)  weights -> wave-contiguous f16 panels
//                   [3328,4480)  offsets -> packed coords {4 f16 w, 4 u16 pix}
__global__ __launch_bounds__(256) void prep_all_kernel(
    const float* __restrict__ x, const float* __restrict__ w,
    const float* __restrict__ offset,
    unsigned short* __restrict__ xb, unsigned short* __restrict__ w3s,
    unsigned short* __restrict__ coords) {
  int tid = threadIdx.x;
  if (blockIdx.x < 1024) {
    // block = (bn, y, x-half); thread = (c8, x4): 8 channels x 4 x's.
    int bn  = blockIdx.x >> 7;
    int rem = blockIdx.x & 127;
    int y   = rem >> 1;
    int xh  = rem & 1;
    int c8  = tid & 31;            // channel group (8 ch)
    int x4  = tid >> 5;            // 0..7 -> x quartet
    int x0  = xh * 32 + x4 * 4;

    const float* src = x + ((size_t)(bn * 256 + c8 * 8)) * 4096 + y * 64 + x0;
    float4 v[8];
#pragma unroll
    for (int r = 0; r < 8; ++r)
      v[r] = *(const float4*)(src + (size_t)r * 4096);

    unsigned short* dst = xb + (((size_t)(bn * 64 + y) * 64 + x0)) * 256 + c8 * 8;
#pragma unroll
    for (int i = 0; i < 4; ++i) {
      float e[8];
      e[0] = (&v[0].x)[i]; e[1] = (&v[1].x)[i];
      e[2] = (&v[2].x)[i]; e[3] = (&v[3].x)[i];
      e[4] = (&v[4].x)[i]; e[5] = (&v[5].x)[i];
      e[6] = (&v[6].x)[i]; e[7] = (&v[7].x)[i];
      uint4 pk;
      pk.x = packh2f(e[0], e[1]);
      pk.y = packh2f(e[2], e[3]);
      pk.z = packh2f(e[4], e[5]);
      pk.w = packh2f(e[6], e[7]);
      *(uint4*)(dst + (size_t)i * 256) = pk;
    }
  } else if (blockIdx.x < 3328) {
    // w3s layout: chunk t (16384 shorts) = [wcol(4)][nn(4)][ks(2)][lane(64)][e(8)]
    int idx = (blockIdx.x - 1024) * 256 + tid;   // < 589824
    int t    = idx >> 14;
    int r2   = idx & 16383;
    int e    = r2 & 7;
    int lane = (r2 >> 3) & 63;
    int ks   = (r2 >> 9) & 1;
    int nn   = (r2 >> 10) & 3;
    int wcol = (r2 >> 12) & 3;
    int oc = wcol * 64 + nn * 16 + (lane & 15);
    int kk = (ks * 4 + (lane >> 4)) * 8 + e;
    int c  = (t & 3) * 64 + kk;
    int k  = t >> 2;
    w3s[idx] = __builtin_bit_cast(unsigned short, __float2half(w[(oc * 256 + c) * 9 + k]));
  } else {
    int idx = (blockIdx.x - 3328) * 256 + tid;   // < 294912
    int ow  = idx & 63;
    int oh  = (idx >> 6) & 63;
    int r   = idx >> 12;          // bn*9 + k
    int k   = r % 9;
    int bn  = r / 9;
    int ky = k / 3 - 1;
    int kx = k % 3 - 1;
    float offy = offset[((bn * 18 + 2 * k    ) * 64 + oh) * 64 + ow];
    float offx = offset[((bn * 18 + 2 * k + 1) * 64 + oh) * 64 + ow];
    float y = (float)(oh + ky) + offy;
    float x2 = (float)(ow + kx) + offx;
    float y0f = floorf(y), x0f = floorf(x2);
    float fy = y - y0f, fx = x2 - x0f;
    int y0 = (int)y0f, x0 = (int)x0f;
    int y1 = y0 + 1, x1 = x0 + 1;
    float vy0 = (y0 >= 0 && y0 <= 63) ? 1.0f : 0.0f;
    float vy1 = (y1 >= 0 && y1 <= 63) ? 1.0f : 0.0f;
    float vx0 = (x0 >= 0 && x0 <= 63) ? 1.0f : 0.0f;
    float vx1 = (x1 >= 0 && x1 <= 63) ? 1.0f : 0.0f;
    float wy0 = (1.0f - fy) * vy0, wy1 = fy * vy1;
    float wx0 = (1.0f - fx) * vx0, wx1 = fx * vx1;
    int y0c = min(max(y0, 0), 63), y1c = min(max(y1, 0), 63);
    int x0c = min(max(x0, 0), 63), x1c = min(max(x1, 0), 63);
    unsigned short ent[8];
    ent[0] = __builtin_bit_cast(unsigned short, __float2half(wy0 * wx0));
    ent[1] = __builtin_bit_cast(unsigned short, __float2half(wy0 * wx1));
    ent[2] = __builtin_bit_cast(unsigned short, __float2half(wy1 * wx0));
    ent[3] = __builtin_bit_cast(unsigned short, __float2half(wy1 * wx1));
    ent[4] = (unsigned short)(y0c * 64 + x0c);
    ent[5] = (unsigned short)(y0c * 64 + x1c);
    ent[6] = (unsigned short)(y1c * 64 + x0c);
    ent[7] = (unsigned short)(y1c * 64 + x1c);
    *(uint4*)(coords + (size_t)idx * 8) = *(const uint4*)ent;
  }
}

// ---- main: 512 blocks x 512 threads; tile 64 rows x 256 oc; wave 32x64 ----
// (R15 verbatim -- best verified configuration)
__global__ __launch_bounds__(512, 4) void deform_mfma_kernel(
    const unsigned short* __restrict__ xb,      // NHWC f16
    const unsigned short* __restrict__ coords,  // packed coord entries
    const unsigned short* __restrict__ w3s,     // wave-contiguous panels f16
    float* __restrict__ out) {                  // (8, 256, 64, 64) fp32
  __shared__ __align__(16) unsigned short At[2][64 * 64];
  __shared__ __align__(16) unsigned short Bt[2][16384];

  int bn  = blockIdx.x & 7;      // XCD swizzle
  int oh  = blockIdx.x >> 3;     // 0..63
  int tid = threadIdx.x;

  int w    = tid >> 6;            // wave 0..7
  int lane = tid & 63;
  int wrow = w & 1;               // 32-row half
  int wcol = w >> 1;              // 64-oc quarter
  int mrow = lane & 15;
  int quad = lane >> 4;

  int srow = tid >> 3;             // 0..63
  int sg   = tid & 7;

  const char* xbc = (const char*)(xb + (size_t)bn * (64 * 64 * 256));
  const unsigned short* cb = coords + ((size_t)((bn * 9) * 64 + oh) * 64 + srow) * 8;

  int aw0  = srow * 64 + ((sg ^ (srow & 7)) * 8);   // XOR-swizzled slot (shorts)
  int grp0 = quad ^ (mrow & 7);                     // ks=0 A frag group
  int grp1 = (4 + quad) ^ (mrow & 7);               // ks=1 A frag group
  int a_base = (wrow * 32 + mrow) * 64;             // + m*1024 (shorts)
  int b_off  = wcol * 4096 + lane * 8;              // shorts; + (nn*2+ks)*512
  int d_off  = w * 2048 + lane * 8;                 // shorts; DMA src slice

  f32x4 acc[2][4] = {};

  __half2 w00, w01, w02, w03;
  uint32_t o00, o01, o02, o03;
  uint4 cn;
  uint4 ga0, ga1, ga2, ga3;       // in-flight corner gathers

#define EBAR()                                                                  \
  {                                                                             \
    asm volatile("s_waitcnt vmcnt(0) lgkmcnt(0)" ::: "memory");                 \
    __builtin_amdgcn_sched_barrier(0);                                          \
    __builtin_amdgcn_s_barrier();                                               \
    asm volatile("" ::: "memory");                                              \
  }
#define CBAR()                                                                  \
  {                                                                             \
    asm volatile("s_waitcnt lgkmcnt(0)" ::: "memory");                          \
    __builtin_amdgcn_s_barrier();                                               \
    asm volatile("" ::: "memory");                                              \
  }
#define VMW(N)                                                                  \
  {                                                                             \
    asm volatile("s_waitcnt vmcnt(" #N ")" ::: "memory");                       \
    __builtin_amdgcn_sched_barrier(0);                                          \
  }

#define BDMA(TT, BB)                                                            \
  {                                                                             \
    const unsigned short* src = w3s + (size_t)(TT) * 16384 + d_off;             \
    unsigned short* dst = &Bt[BB][0] + w * 2048;                                \
    _Pragma("unroll")                                                           \
    for (int j = 0; j < 4; ++j) {                                               \
      __builtin_amdgcn_global_load_lds(                                         \
          (const __attribute__((address_space(1))) void*)(src + j * 512),       \
          (__attribute__((address_space(3))) void*)(dst + j * 512),             \
          16, 0, 0);                                                            \
    }                                                                           \
  }

#define TAPSETUP_R(CE)                                                          \
  {                                                                             \
    w00 = duplo((CE).x); w01 = duphi((CE).x);                                   \
    w02 = duplo((CE).y); w03 = duphi((CE).y);                                   \
    o00 = (((CE).z & 0xffffu) << 9) + sg * 16;                                  \
    o01 = (((CE).z >> 16) << 9) + sg * 16;                                      \
    o02 = (((CE).w & 0xffffu) << 9) + sg * 16;                                  \
    o03 = (((CE).w >> 16) << 9) + sg * 16;                                      \
  }

#define AGATHER(TT)                                                             \
  {                                                                             \
    ga0 = *(const uint4*)(xbc + o00 + ((TT) & 3) * 128);                        \
    ga1 = *(const uint4*)(xbc + o01 + ((TT) & 3) * 128);                        \
    ga2 = *(const uint4*)(xbc + o02 + ((TT) & 3) * 128);                        \
    ga3 = *(const uint4*)(xbc + o03 + ((TT) & 3) * 128);                        \
  }

#define AMATH(ATP)                                                              \
  {                                                                             \
    VMW(4)                                                                      \
    __half2 r0 = __hmul2(h2(ga0.x), w00);                                       \
    r0 = __hfma2(h2(ga1.x), w01, r0); r0 = __hfma2(h2(ga2.x), w02, r0);         \
    r0 = __hfma2(h2(ga3.x), w03, r0);                                           \
    __half2 r1 = __hmul2(h2(ga0.y), w00);                                       \
    r1 = __hfma2(h2(ga1.y), w01, r1); r1 = __hfma2(h2(ga2.y), w02, r1);         \
    r1 = __hfma2(h2(ga3.y), w03, r1);                                           \
    __half2 r2 = __hmul2(h2(ga0.z), w00);                                       \
    r2 = __hfma2(h2(ga1.z), w01, r2); r2 = __hfma2(h2(ga2.z), w02, r2);         \
    r2 = __hfma2(h2(ga3.z), w03, r2);                                           \
    __half2 r3 = __hmul2(h2(ga0.w), w00);                                       \
    r3 = __hfma2(h2(ga1.w), w01, r3); r3 = __hfma2(h2(ga2.w), w02, r3);         \
    r3 = __hfma2(h2(ga3.w), w03, r3);                                           \
    uint4 pk;                                                                   \
    pk.x = __builtin_bit_cast(uint32_t, r0);                                    \
    pk.y = __builtin_bit_cast(uint32_t, r1);                                    \
    pk.z = __builtin_bit_cast(uint32_t, r2);                                    \
    pk.w = __builtin_bit_cast(uint32_t, r3);                                    \
    *(uint4*)((ATP) + aw0) = pk;                                                \
  }

#define COMPUTE(ATP, BTP)                                                       \
  {                                                                             \
    half8 bfr[2][4];                                                            \
    _Pragma("unroll")                                                           \
    for (int nn = 0; nn < 4; ++nn) {                                            \
      bfr[0][nn] = *(const half8*)((BTP) + b_off + (nn * 2 + 0) * 512);         \
      bfr[1][nn] = *(const half8*)((BTP) + b_off + (nn * 2 + 1) * 512);         \
    }                                                                           \
    __builtin_amdgcn_s_setprio(1);                                              \
    _Pragma("unroll")                                                           \
    for (int m = 0; m < 2; ++m) {                                               \
      half8 af0 = *(const half8*)((ATP) + a_base + m * 1024 + grp0 * 8);        \
      half8 af1 = *(const half8*)((ATP) + a_base + m * 1024 + grp1 * 8);        \
      _Pragma("unroll")                                                         \
      for (int nn = 0; nn < 4; ++nn) {                                          \
        acc[m][nn] = __builtin_amdgcn_mfma_f32_16x16x32_f16(af0, bfr[0][nn], acc[m][nn], 0, 0, 0); \
        acc[m][nn] = __builtin_amdgcn_mfma_f32_16x16x32_f16(af1, bfr[1][nn], acc[m][nn], 0, 0, 0); \
      }                                                                         \
    }                                                                           \
    __builtin_amdgcn_s_setprio(0);                                              \
  }

  // ---- prologue: coords, gathers(0), DMA(0)->Bt[0], stage A(0) ----
  {
    uint4 ce0 = *(const uint4*)cb;
    TAPSETUP_R(ce0)
  }
  AGATHER(0)
  BDMA(0, 0)
  AMATH(&At[0][0])                   // VMW(4): retires gathers, keeps DMA
  CBAR()

  for (int tap = 0; tap < 9; ++tap) {
#pragma unroll
    for (int cc = 0; cc < 4; ++cc) {
      const int t = tap * 4 + cc;
      // ---- ENTRY: retire DMA(t) (aged), all-wave visibility for Bt[t&1] ----
      EBAR()
      // ---- issue t+1 vmem: coords (oldest), gathers, DMA (newest) ----
      if (t < 35) {
        if (cc == 3) TAPSETUP_R(cn)   // VALU-only; cn retired by prev VMW(4)
        if (cc == 2 && tap < 8) cn = *(const uint4*)(cb + (tap + 1) * 32768);
        AGATHER(t + 1)
        if (cc & 1) { BDMA(t + 1, 0) } else { BDMA(t + 1, 1) }
      }
      // ---- compute chunk t (no vmem wait) ----
      if (cc & 1) { COMPUTE(&At[1][0], &Bt[1][0]) } else { COMPUTE(&At[0][0], &Bt[0][0]) }
      // ---- finish A(t+1) staging: VMW(4) keeps DMA(t+1) in flight ----
      if (t < 35) {
        if (cc & 1) { AMATH(&At[0][0]) } else { AMATH(&At[1][0]) }
      }
      // ---- EXIT: LDS order only; DMA(t+1) crosses in flight ----
      CBAR()
    }
  }

  // ---- epilogue: C/D layout col=lane&15(oc), row=quad*4+reg(ow) ----
  float* outp = out + (size_t)bn * 256 * 4096 + (size_t)oh * 64;
#pragma unroll
  for (int m = 0; m < 2; ++m) {
    int ow0 = wrow * 32 + m * 16 + quad * 4;
#pragma unroll
    for (int nn = 0; nn < 4; ++nn) {
      int oc = wcol * 64 + nn * 16 + mrow;
      *(f32x4*)(outp + (size_t)oc * 4096 + ow0) = acc[m][nn];
    }
  }
#undef EBAR
#undef CBAR
#undef VMW
#undef BDMA
#undef TAPSETUP_R
#undef AGATHER
#undef AMATH
#undef COMPUTE
}

extern "C" void kernel_launch(void* const* d_in, const int* in_sizes, int n_in,
                              void* d_out, int out_size, void* d_ws, size_t ws_size,
                              hipStream_t stream) {
  (void)in_sizes; (void)n_in; (void)out_size; (void)ws_size;
  const float* x      = (const float*)d_in[0];
  const float* offset = (const float*)d_in[1];
  const float* weight = (const float*)d_in[2];
  float* out = (float*)d_out;

  unsigned short* xb     = (unsigned short*)d_ws;                        // 16.78 MB
  unsigned short* w3s    = xb + (size_t)8 * 64 * 64 * 256;               // +1.18 MB
  unsigned short* coords = w3s + (size_t)36 * 16384;                     // +4.72 MB

  prep_all_kernel<<<4480, 256, 0, stream>>>(x, weight, offset, xb, w3s, coords);
  deform_mfma_kernel<<<512, 512, 0, stream>>>(xb, coords, w3s, out);
}